// Round 3
// baseline (1325.378 us; speedup 1.0000x reference)
//
#include <hip/hip_runtime.h>
#include <cfloat>

#define Nn 100000
#define Ee 800000
#define Gg 256
// H=96, NI=32, EI=10, OUT=256, L=3

// ---------------- CSR build ----------------

__global__ __launch_bounds__(512) void k_gptr(const int* __restrict__ batch, int* __restrict__ gptr) {
  int g = threadIdx.x;
  if (g > Gg) return;
  if (g == Gg) { gptr[Gg] = Nn; return; }
  int lo = 0, hi = Nn;
  while (lo < hi) { int mid = (lo + hi) >> 1; if (batch[mid] < g) lo = mid + 1; else hi = mid; }
  gptr[g] = lo;
}

__global__ __launch_bounds__(256) void k_deg(const int* __restrict__ dst, int* __restrict__ deg) {
  int e = blockIdx.x * 256 + threadIdx.x;
  if (e < Ee) atomicAdd(&deg[dst[e]], 1);
}

// block scans 1024 elements (4/thread, 256 threads)
__global__ __launch_bounds__(256) void k_scanA(const int* __restrict__ deg, int* __restrict__ localA,
                                               int* __restrict__ bsum) {
  __shared__ int ts[256];
  int t = threadIdx.x, b = blockIdx.x;
  int base = b * 1024 + t * 4;
  int v[4]; int s = 0;
#pragma unroll
  for (int k = 0; k < 4; k++) { int idx = base + k; v[k] = (idx < Nn) ? deg[idx] : 0; s += v[k]; }
  ts[t] = s; __syncthreads();
  for (int off = 1; off < 256; off <<= 1) {
    int y = (t >= off) ? ts[t - off] : 0;
    __syncthreads();
    ts[t] += y;
    __syncthreads();
  }
  int ex = ts[t] - s;  // exclusive prefix for this thread's chunk
#pragma unroll
  for (int k = 0; k < 4; k++) { int idx = base + k; if (idx < Nn) localA[idx] = ex; ex += v[k]; }
  if (t == 255) bsum[b] = ts[255];
}

__global__ void k_scanB(int* __restrict__ bsum) {
  if (threadIdx.x == 0) {
    const int NB = (Nn + 1023) / 1024;
    int acc = 0;
    for (int b = 0; b < NB; b++) { int v = bsum[b]; bsum[b] = acc; acc += v; }
  }
}

__global__ __launch_bounds__(256) void k_scanC(const int* __restrict__ localA, const int* __restrict__ bsum,
                                               int* __restrict__ rowptr, int* __restrict__ cursor) {
  int i = blockIdx.x * 256 + threadIdx.x;
  if (i < Nn) { int v = localA[i] + bsum[i >> 10]; rowptr[i] = v; cursor[i] = v; }
  if (i == 0) rowptr[Nn] = Ee;
}

__global__ __launch_bounds__(256) void k_fill(const int* __restrict__ dst, int* __restrict__ cursor,
                                              int* __restrict__ elist) {
  int e = blockIdx.x * 256 + threadIdx.x;
  if (e < Ee) { int p = atomicAdd(&cursor[dst[e]], 1); elist[p] = e; }
}

// ---------------- node MLP: h = relu(x @ W + b), x[N,32], W[32,96] ----------------

__global__ __launch_bounds__(256) void k_node_mlp(const float* __restrict__ x, const float* __restrict__ W,
                                                  const float* __restrict__ b, float* __restrict__ h) {
  __shared__ float xs[16][33];
  __shared__ float Ws[32 * 96];
  __shared__ float bs[96];
  int t = threadIdx.x;
  int n0 = blockIdx.x * 16;
  for (int i = t; i < 32 * 96; i += 256) Ws[i] = W[i];
  if (t < 96) bs[t] = b[t];
  for (int i = t; i < 512; i += 256) {
    int nl = i >> 5, k = i & 31; int n = n0 + nl;
    xs[nl][k] = (n < Nn) ? x[n * 32 + k] : 0.f;
  }
  __syncthreads();
#pragma unroll
  for (int p = 0; p < 6; p++) {
    int oi = t + p * 256; int nl = oi / 96, j = oi % 96; int n = n0 + nl;
    if (n < Nn) {
      float acc = bs[j];
#pragma unroll
      for (int k = 0; k < 32; k++) acc += xs[nl][k] * Ws[k * 96 + j];
      h[n * 96 + j] = fmaxf(acc, 0.f);
    }
  }
}

// ---------------- aggregation: agg[nd] = sum_{e: dst=nd} relu(h[src_e] + relu(ea_e@eW+eb)) ----------------
// v3: edge-MLP weights live in REGISTERS (Ws[k][t] fixed per thread) -> zero per-edge
// ds_reads for weights; eattr staging parallelized over (edge,k) pairs; unroll 8 keeps
// 8 h[src] gathers in flight per wave.

#define ACHUNK 32

__global__ __launch_bounds__(128) void k_agg(const float* __restrict__ h, const float* __restrict__ eattr,
                                             const int* __restrict__ srcArr, const int* __restrict__ rowptr,
                                             const int* __restrict__ elist, const float* __restrict__ eW,
                                             const float* __restrict__ eb, float* __restrict__ agg) {
  __shared__ int sL[ACHUNK];
  __shared__ float eaL[ACHUNK][10];
  int t = threadIdx.x;
  int nd = blockIdx.x;
  int tf = (t < 96) ? t : 0;
  float wreg[10];
#pragma unroll
  for (int k = 0; k < 10; k++) wreg[k] = eW[k * 96 + tf];
  float breg = eb[tf];
  int beg = rowptr[nd], end = rowptr[nd + 1];
  float acc = 0.f;
  for (int cs = beg; cs < end; cs += ACHUNK) {
    int m = min(ACHUNK, end - cs);
    __syncthreads();   // previous iteration's reads of sL/eaL done
    if (t < m) sL[t] = srcArr[elist[cs + t]];
    for (int i = t; i < 10 * m; i += 128) {
      int ii = i / 10, k = i - ii * 10;
      int e = elist[cs + ii];          // redundant load, L1-hit
      eaL[ii][k] = eattr[e * 10 + k];
    }
    __syncthreads();
    if (t < 96) {
#pragma unroll 8
      for (int i = 0; i < m; i++) {
        int src = sL[i];
        float hv = h[src * 96 + t];
        float ej = breg;
#pragma unroll
        for (int k = 0; k < 10; k++) ej += eaL[i][k] * wreg[k];
        acc += fmaxf(hv + fmaxf(ej, 0.f), 0.f);
      }
    }
  }
  if (t < 96) agg[nd * 96 + t] = acc;
}

// ---------------- per-layer MLP: z = relu(z0@W1+b1)@W2+b2, z0 = (1+eps)*h + agg ----------------
// NOTE: agg and z may alias (block reads only its own rows before writing them).

__global__ __launch_bounds__(256) void k_mlp(const float* __restrict__ h, const float* agg,
                                             const float* __restrict__ W1, const float* __restrict__ b1,
                                             const float* __restrict__ W2, const float* __restrict__ b2,
                                             const float* __restrict__ epsA, int layer, float* z) {
  __shared__ float in_s[32][97];
  __shared__ float mid[32][97];
  __shared__ float Ws[96 * 96];
  int t = threadIdx.x;
  int n0 = blockIdx.x * 32;
  float epsv = 1.0f + epsA[layer];
  for (int i = t; i < 3072; i += 256) {
    int nl = i / 96, k = i % 96; int n = n0 + nl;
    in_s[nl][k] = (n < Nn) ? (epsv * h[n * 96 + k] + agg[n * 96 + k]) : 0.f;
  }
  for (int i = t; i < 9216; i += 256) Ws[i] = W1[i];
  __syncthreads();
  int nl = t >> 3, jb = t & 7;   // node, feature-block
  float acc[12];
#pragma unroll
  for (int jj = 0; jj < 12; jj++) acc[jj] = b1[jb * 12 + jj];
  for (int k = 0; k < 96; k++) {
    float a = in_s[nl][k];
#pragma unroll
    for (int jj = 0; jj < 12; jj++) acc[jj] += a * Ws[k * 96 + jb * 12 + jj];
  }
#pragma unroll
  for (int jj = 0; jj < 12; jj++) mid[nl][jb * 12 + jj] = fmaxf(acc[jj], 0.f);
  __syncthreads();               // all reads of Ws (W1) done
  for (int i = t; i < 9216; i += 256) Ws[i] = W2[i];
  __syncthreads();
#pragma unroll
  for (int jj = 0; jj < 12; jj++) acc[jj] = b2[jb * 12 + jj];
  for (int k = 0; k < 96; k++) {
    float a = mid[nl][k];
#pragma unroll
    for (int jj = 0; jj < 12; jj++) acc[jj] += a * Ws[k * 96 + jb * 12 + jj];
  }
  int n = n0 + nl;
  if (n < Nn) {
#pragma unroll
    for (int jj = 0; jj < 12; jj++) z[n * 96 + jb * 12 + jj] = acc[jj];
  }
}

// ---------------- GraphNorm stats: meanms = (S1/c)*ms ; inv = rsqrt(var+1e-5) ----------------

__global__ __launch_bounds__(192) void k_stats(const float* __restrict__ z, const int* __restrict__ gptr,
                                               const float* __restrict__ ms, float* __restrict__ meanms,
                                               float* __restrict__ inv) {
  __shared__ float sh1[2][96], sh2[2][96];
  int g = blockIdx.x, t = threadIdx.x;
  int j = t % 96, half = t / 96;
  int beg = gptr[g], end = gptr[g + 1];
  float s1 = 0.f, s2 = 0.f;
  for (int n = beg + half; n < end; n += 2) { float v = z[n * 96 + j]; s1 += v; s2 += v * v; }
  sh1[half][j] = s1; sh2[half][j] = s2;
  __syncthreads();
  if (t < 96) {
    float S1 = sh1[0][t] + sh1[1][t], S2 = sh2[0][t] + sh2[1][t];
    float c = (float)max(end - beg, 1);
    float m = S1 / c;
    float mm = m * ms[t];
    float var = S2 / c - 2.f * mm * m + mm * mm;
    var = fmaxf(var, 0.f);
    meanms[g * 96 + t] = mm;
    inv[g * 96 + t] = rsqrtf(var + 1e-5f);
  }
}

// ---------------- normalize + residual: h_new = relu(gw*(z-mm)*inv+gb) + h_old ----------------

__global__ __launch_bounds__(256) void k_norm(const float* __restrict__ z, const float* __restrict__ h_old,
                                              const int* __restrict__ batch, const float* __restrict__ meanms,
                                              const float* __restrict__ inv, const float* __restrict__ gw,
                                              const float* __restrict__ gb, float* __restrict__ h_new) {
  int i = blockIdx.x * 256 + threadIdx.x;
  if (i >= Nn * 96) return;
  int n = i / 96, j = i % 96;
  int g = batch[n];
  float outv = z[i] - meanms[g * 96 + j];
  float zn = gw[j] * outv * inv[g * 96 + j] + gb[j];
  h_new[i] = fmaxf(zn, 0.f) + h_old[i];
}

// ---------------- pooling + LayerNorm + output MLP ----------------

__global__ __launch_bounds__(256) void k_pool_out(const float* __restrict__ h, const int* __restrict__ gptr,
                                                  const float* __restrict__ lng, const float* __restrict__ lnb,
                                                  const float* __restrict__ W1, const float* __restrict__ b1,
                                                  const float* __restrict__ W2, const float* __restrict__ b2,
                                                  float* __restrict__ out) {
  __shared__ float sh1[2][96], sh2[2][96];
  __shared__ float gbuf[192];
  __shared__ float rs[4], rq[4];
  __shared__ float s_mu, s_rstd;
  __shared__ float inter[96];
  int g = blockIdx.x, t = threadIdx.x;
  int beg = gptr[g], end = gptr[g + 1];
  if (t < 192) {
    int j = t % 96, half = t / 96;
    float s = 0.f, m = -INFINITY;
    for (int n = beg + half; n < end; n += 2) { float v = h[n * 96 + j]; s += v; m = fmaxf(m, v); }
    sh1[half][j] = s; sh2[half][j] = m;
  }
  __syncthreads();
  if (t < 96) {
    float c = (float)max(end - beg, 1);
    gbuf[t] = (sh1[0][t] + sh1[1][t]) / c;
    gbuf[96 + t] = fmaxf(sh2[0][t], sh2[1][t]);
  }
  __syncthreads();
  float sv = (t < 192) ? gbuf[t] : 0.f;
  float qv = sv * sv;
#pragma unroll
  for (int off = 32; off; off >>= 1) { sv += __shfl_down(sv, off); qv += __shfl_down(qv, off); }
  if ((t & 63) == 0) { rs[t >> 6] = sv; rq[t >> 6] = qv; }
  __syncthreads();
  if (t == 0) {
    float S = rs[0] + rs[1] + rs[2] + rs[3];
    float Q = rq[0] + rq[1] + rq[2] + rq[3];
    float mu = S / 192.f;
    float va = Q / 192.f - mu * mu;
    s_mu = mu; s_rstd = rsqrtf(fmaxf(va, 0.f) + 1e-5f);
  }
  __syncthreads();
  if (t < 192) gbuf[t] = (gbuf[t] - s_mu) * s_rstd * lng[t] + lnb[t];
  __syncthreads();
  if (t < 96) {
    float a = b1[t];
    for (int k = 0; k < 192; k++) a += gbuf[k] * W1[k * 96 + t];
    inter[t] = fmaxf(a, 0.f);
  }
  __syncthreads();
  {
    float a = b2[t];
    for (int j = 0; j < 96; j++) a += inter[j] * W2[j * 256 + t];
    out[g * 256 + t] = a;
  }
}

// ---------------- host ----------------

extern "C" void kernel_launch(void* const* d_in, const int* in_sizes, int n_in,
                              void* d_out, int out_size, void* d_ws, size_t ws_size,
                              hipStream_t stream) {
  (void)in_sizes; (void)n_in; (void)out_size; (void)ws_size;
  const float* x     = (const float*)d_in[0];
  const float* eattr = (const float*)d_in[1];
  const int*   eidx2 = (const int*)  d_in[2];
  const int*   batch = (const int*)  d_in[3];
  const float* nodeW = (const float*)d_in[4];
  const float* nodeb = (const float*)d_in[5];
  const float* edgeW = (const float*)d_in[6];
  const float* edgeb = (const float*)d_in[7];
  const float* mlpW1 = (const float*)d_in[8];
  const float* mlpb1 = (const float*)d_in[9];
  const float* mlpW2 = (const float*)d_in[10];
  const float* mlpb2 = (const float*)d_in[11];
  const float* epsA  = (const float*)d_in[12];
  const float* gnw   = (const float*)d_in[13];
  const float* gnb   = (const float*)d_in[14];
  const float* gnms  = (const float*)d_in[15];
  const float* lng   = (const float*)d_in[16];
  const float* lnb   = (const float*)d_in[17];
  const float* oW1   = (const float*)d_in[18];
  const float* ob1   = (const float*)d_in[19];
  const float* oW2   = (const float*)d_in[20];
  const float* ob2   = (const float*)d_in[21];
  float* out = (float*)d_out;

  const int* srcArr = eidx2;        // edge_index[0]
  const int* dstArr = eidx2 + Ee;   // edge_index[1]

  char* p = (char*)d_ws;
  auto carve = [&](size_t bytes) -> void* {
    void* r = (void*)p;
    p += ((bytes + 255) & ~(size_t)255);
    return r;
  };
  float* h_a   = (float*)carve((size_t)Nn * 96 * 4);
  float* h_b   = (float*)carve((size_t)Nn * 96 * 4);
  float* aggz  = (float*)carve((size_t)Nn * 96 * 4);  // agg, aliased as z
  int* rowptr  = (int*)carve((size_t)(Nn + 1) * 4);
  int* cursor  = (int*)carve((size_t)Nn * 4);
  int* deg     = (int*)carve((size_t)Nn * 4);
  int* localA  = (int*)carve((size_t)Nn * 4);
  int* bsum    = (int*)carve(512);
  int* elist   = (int*)carve((size_t)Ee * 4);
  int* gptr    = (int*)carve((size_t)(Gg + 1) * 4);
  float* meanms= (float*)carve((size_t)Gg * 96 * 4);
  float* invv  = (float*)carve((size_t)Gg * 96 * 4);

  hipMemsetAsync(deg, 0, (size_t)Nn * 4, stream);
  k_gptr<<<1, 512, 0, stream>>>(batch, gptr);
  k_deg<<<(Ee + 255) / 256, 256, 0, stream>>>(dstArr, deg);
  k_scanA<<<(Nn + 1023) / 1024, 256, 0, stream>>>(deg, localA, bsum);
  k_scanB<<<1, 64, 0, stream>>>(bsum);
  k_scanC<<<(Nn + 255) / 256, 256, 0, stream>>>(localA, bsum, rowptr, cursor);
  k_fill<<<(Ee + 255) / 256, 256, 0, stream>>>(dstArr, cursor, elist);

  k_node_mlp<<<(Nn + 15) / 16, 256, 0, stream>>>(x, nodeW, nodeb, h_a);

  float* hc = h_a;
  float* hn = h_b;
  for (int i = 0; i < 3; i++) {
    k_agg<<<Nn, 128, 0, stream>>>(hc, eattr, srcArr, rowptr, elist, edgeW, edgeb, aggz);
    k_mlp<<<Nn / 32, 256, 0, stream>>>(hc, aggz, mlpW1 + i * 9216, mlpb1 + i * 96,
                                       mlpW2 + i * 9216, mlpb2 + i * 96, epsA, i, aggz);
    k_stats<<<Gg, 192, 0, stream>>>(aggz, gptr, gnms + i * 96, meanms, invv);
    k_norm<<<(Nn * 96 + 255) / 256, 256, 0, stream>>>(aggz, hc, batch, meanms, invv,
                                                      gnw + i * 96, gnb + i * 96, hn);
    float* tmp = hc; hc = hn; hn = tmp;
  }

  k_pool_out<<<Gg, 256, 0, stream>>>(hc, gptr, lng, lnb, oW1, ob1, oW2, ob2, out);
}

// Round 4
// 1197.603 us; speedup vs baseline: 1.1067x; 1.1067x over previous
//
#include <hip/hip_runtime.h>
#include <hip/hip_bf16.h>
#include <cfloat>

#define Nn 100000
#define Ee 800000
#define Gg 256
// H=96, NI=32, EI=10, OUT=256, L=3

// ---------------- CSR build ----------------

__global__ __launch_bounds__(512) void k_gptr(const int* __restrict__ batch, int* __restrict__ gptr) {
  int g = threadIdx.x;
  if (g > Gg) return;
  if (g == Gg) { gptr[Gg] = Nn; return; }
  int lo = 0, hi = Nn;
  while (lo < hi) { int mid = (lo + hi) >> 1; if (batch[mid] < g) lo = mid + 1; else hi = mid; }
  gptr[g] = lo;
}

__global__ __launch_bounds__(256) void k_deg(const int* __restrict__ dst, int* __restrict__ deg) {
  int e = blockIdx.x * 256 + threadIdx.x;
  if (e < Ee) atomicAdd(&deg[dst[e]], 1);
}

// block scans 1024 elements (4/thread, 256 threads)
__global__ __launch_bounds__(256) void k_scanA(const int* __restrict__ deg, int* __restrict__ localA,
                                               int* __restrict__ bsum) {
  __shared__ int ts[256];
  int t = threadIdx.x, b = blockIdx.x;
  int base = b * 1024 + t * 4;
  int v[4]; int s = 0;
#pragma unroll
  for (int k = 0; k < 4; k++) { int idx = base + k; v[k] = (idx < Nn) ? deg[idx] : 0; s += v[k]; }
  ts[t] = s; __syncthreads();
  for (int off = 1; off < 256; off <<= 1) {
    int y = (t >= off) ? ts[t - off] : 0;
    __syncthreads();
    ts[t] += y;
    __syncthreads();
  }
  int ex = ts[t] - s;  // exclusive prefix for this thread's chunk
#pragma unroll
  for (int k = 0; k < 4; k++) { int idx = base + k; if (idx < Nn) localA[idx] = ex; ex += v[k]; }
  if (t == 255) bsum[b] = ts[255];
}

__global__ void k_scanB(int* __restrict__ bsum) {
  if (threadIdx.x == 0) {
    const int NB = (Nn + 1023) / 1024;
    int acc = 0;
    for (int b = 0; b < NB; b++) { int v = bsum[b]; bsum[b] = acc; acc += v; }
  }
}

__global__ __launch_bounds__(256) void k_scanC(const int* __restrict__ localA, const int* __restrict__ bsum,
                                               int* __restrict__ rowptr, int* __restrict__ cursor) {
  int i = blockIdx.x * 256 + threadIdx.x;
  if (i < Nn) { int v = localA[i] + bsum[i >> 10]; rowptr[i] = v; cursor[i] = v; }
  if (i == 0) rowptr[Nn] = Ee;
}

__global__ __launch_bounds__(256) void k_fill(const int* __restrict__ dst, int* __restrict__ cursor,
                                              int* __restrict__ elist) {
  int e = blockIdx.x * 256 + threadIdx.x;
  if (e < Ee) { int p = atomicAdd(&cursor[dst[e]], 1); elist[p] = e; }
}

// ---------------- edge MLP precompute (layer-invariant): ePerm[q] = relu(eattr[elist[q]]@eW+eb) ----------------
// Also builds srcPerm[q] = srcArr[elist[q]] so k_agg streams both contiguously.

#define EB 128

__global__ __launch_bounds__(192) void k_edge_mlp(const float* __restrict__ eattr, const int* __restrict__ elist,
                                                  const int* __restrict__ srcArr, const float* __restrict__ eW,
                                                  const float* __restrict__ eb, __hip_bfloat16* __restrict__ ePerm,
                                                  int* __restrict__ srcPerm) {
  __shared__ float ea[EB][10];
  __shared__ float Ws[10 * 96];
  __shared__ float bs[96];
  int t = threadIdx.x;
  int q0 = blockIdx.x * EB;
  int m = min(EB, Ee - q0);
  for (int i = t; i < 960; i += 192) Ws[i] = eW[i];
  if (t < 96) bs[t] = eb[t];
  for (int i = t; i < m; i += 192) srcPerm[q0 + i] = srcArr[elist[q0 + i]];
  for (int i = t; i < 10 * m; i += 192) {
    int ii = i / 10, k = i - ii * 10;
    int e = elist[q0 + ii];             // redundant load, L1-hit
    ea[ii][k] = eattr[e * 10 + k];
  }
  __syncthreads();
  int j = t % 96, sub = t / 96;         // sub in {0,1}
  for (int i = sub; i < m; i += 2) {
    float acc = bs[j];
#pragma unroll
    for (int k = 0; k < 10; k++) acc += ea[i][k] * Ws[k * 96 + j];
    ePerm[(size_t)(q0 + i) * 96 + j] = __float2bfloat16(fmaxf(acc, 0.f));
  }
}

// ---------------- node MLP: h = relu(x @ W + b), x[N,32], W[32,96] ----------------

__global__ __launch_bounds__(256) void k_node_mlp(const float* __restrict__ x, const float* __restrict__ W,
                                                  const float* __restrict__ b, float* __restrict__ h) {
  __shared__ float xs[16][33];
  __shared__ float Ws[32 * 96];
  __shared__ float bs[96];
  int t = threadIdx.x;
  int n0 = blockIdx.x * 16;
  for (int i = t; i < 32 * 96; i += 256) Ws[i] = W[i];
  if (t < 96) bs[t] = b[t];
  for (int i = t; i < 512; i += 256) {
    int nl = i >> 5, k = i & 31; int n = n0 + nl;
    xs[nl][k] = (n < Nn) ? x[n * 32 + k] : 0.f;
  }
  __syncthreads();
#pragma unroll
  for (int p = 0; p < 6; p++) {
    int oi = t + p * 256; int nl = oi / 96, j = oi % 96; int n = n0 + nl;
    if (n < Nn) {
      float acc = bs[j];
#pragma unroll
      for (int k = 0; k < 32; k++) acc += xs[nl][k] * Ws[k * 96 + j];
      h[n * 96 + j] = fmaxf(acc, 0.f);
    }
  }
}

// ---------------- aggregation (fast path): agg[nd] = sum relu(h[srcPerm[q]] + ePerm[q]) ----------------
// Edge messages pre-reluted in ePerm (bf16, contiguous in q). Inner loop: 1 gather + 1 stream.

#define ACHUNK 32

__global__ __launch_bounds__(128) void k_agg_pre(const float* __restrict__ h,
                                                 const __hip_bfloat16* __restrict__ ePerm,
                                                 const int* __restrict__ srcPerm,
                                                 const int* __restrict__ rowptr,
                                                 float* __restrict__ agg) {
  __shared__ int sL[ACHUNK];
  int t = threadIdx.x;
  int nd = blockIdx.x;
  int beg = rowptr[nd], end = rowptr[nd + 1];
  float acc = 0.f;
  for (int cs = beg; cs < end; cs += ACHUNK) {
    int m = min(ACHUNK, end - cs);
    __syncthreads();   // previous iteration's reads of sL done
    if (t < m) sL[t] = srcPerm[cs + t];
    __syncthreads();
    if (t < 96) {
#pragma unroll 4
      for (int i = 0; i < m; i++) {
        int src = sL[i];
        float hv = h[src * 96 + t];
        float ef = __bfloat162float(ePerm[(size_t)(cs + i) * 96 + t]);
        acc += fmaxf(hv + ef, 0.f);
      }
    }
  }
  if (t < 96) agg[nd * 96 + t] = acc;
}

// ---------------- aggregation (fallback, round-2 proven): recompute edge MLP on the fly ----------------

__global__ __launch_bounds__(128) void k_agg(const float* __restrict__ h, const float* __restrict__ eattr,
                                             const int* __restrict__ srcArr, const int* __restrict__ rowptr,
                                             const int* __restrict__ elist, const float* __restrict__ eW,
                                             const float* __restrict__ eb, float* __restrict__ agg) {
  __shared__ float Ws[10 * 96];
  __shared__ float bs_s[96];
  __shared__ int sL[ACHUNK];
  __shared__ float eaL[ACHUNK][10];
  int t = threadIdx.x;
  int nd = blockIdx.x;
  for (int i = t; i < 960; i += 128) Ws[i] = eW[i];
  if (t < 96) bs_s[t] = eb[t];
  int beg = rowptr[nd], end = rowptr[nd + 1];
  float acc = 0.f;
  for (int cs = beg; cs < end; cs += ACHUNK) {
    int m = min(ACHUNK, end - cs);
    __syncthreads();
    if (t < m) sL[t] = srcArr[elist[cs + t]];
    for (int i = t; i < 10 * m; i += 128) {
      int ii = i / 10, k = i - ii * 10;
      int e = elist[cs + ii];
      eaL[ii][k] = eattr[e * 10 + k];
    }
    __syncthreads();
    if (t < 96) {
#pragma unroll 4
      for (int i = 0; i < m; i++) {
        int src = sL[i];
        float ej = bs_s[t];
#pragma unroll
        for (int k = 0; k < 10; k++) ej += eaL[i][k] * Ws[k * 96 + t];
        ej = fmaxf(ej, 0.f);
        acc += fmaxf(h[src * 96 + t] + ej, 0.f);
      }
    }
  }
  if (t < 96) agg[nd * 96 + t] = acc;
}

// ---------------- per-layer MLP: z = relu(z0@W1+b1)@W2+b2, z0 = (1+eps)*h + agg ----------------
// NOTE: agg and z may alias (block reads only its own rows before writing them).

__global__ __launch_bounds__(256) void k_mlp(const float* __restrict__ h, const float* agg,
                                             const float* __restrict__ W1, const float* __restrict__ b1,
                                             const float* __restrict__ W2, const float* __restrict__ b2,
                                             const float* __restrict__ epsA, int layer, float* z) {
  __shared__ float in_s[32][97];
  __shared__ float mid[32][97];
  __shared__ float Ws[96 * 96];
  int t = threadIdx.x;
  int n0 = blockIdx.x * 32;
  float epsv = 1.0f + epsA[layer];
  for (int i = t; i < 3072; i += 256) {
    int nl = i / 96, k = i % 96; int n = n0 + nl;
    in_s[nl][k] = (n < Nn) ? (epsv * h[n * 96 + k] + agg[n * 96 + k]) : 0.f;
  }
  for (int i = t; i < 9216; i += 256) Ws[i] = W1[i];
  __syncthreads();
  int nl = t >> 3, jb = t & 7;   // node, feature-block
  float acc[12];
#pragma unroll
  for (int jj = 0; jj < 12; jj++) acc[jj] = b1[jb * 12 + jj];
  for (int k = 0; k < 96; k++) {
    float a = in_s[nl][k];
#pragma unroll
    for (int jj = 0; jj < 12; jj++) acc[jj] += a * Ws[k * 96 + jb * 12 + jj];
  }
#pragma unroll
  for (int jj = 0; jj < 12; jj++) mid[nl][jb * 12 + jj] = fmaxf(acc[jj], 0.f);
  __syncthreads();               // all reads of Ws (W1) done
  for (int i = t; i < 9216; i += 256) Ws[i] = W2[i];
  __syncthreads();
#pragma unroll
  for (int jj = 0; jj < 12; jj++) acc[jj] = b2[jb * 12 + jj];
  for (int k = 0; k < 96; k++) {
    float a = mid[nl][k];
#pragma unroll
    for (int jj = 0; jj < 12; jj++) acc[jj] += a * Ws[k * 96 + jb * 12 + jj];
  }
  int n = n0 + nl;
  if (n < Nn) {
#pragma unroll
    for (int jj = 0; jj < 12; jj++) z[n * 96 + jb * 12 + jj] = acc[jj];
  }
}

// ---------------- GraphNorm stats: meanms = (S1/c)*ms ; inv = rsqrt(var+1e-5) ----------------

__global__ __launch_bounds__(192) void k_stats(const float* __restrict__ z, const int* __restrict__ gptr,
                                               const float* __restrict__ ms, float* __restrict__ meanms,
                                               float* __restrict__ inv) {
  __shared__ float sh1[2][96], sh2[2][96];
  int g = blockIdx.x, t = threadIdx.x;
  int j = t % 96, half = t / 96;
  int beg = gptr[g], end = gptr[g + 1];
  float s1 = 0.f, s2 = 0.f;
  for (int n = beg + half; n < end; n += 2) { float v = z[n * 96 + j]; s1 += v; s2 += v * v; }
  sh1[half][j] = s1; sh2[half][j] = s2;
  __syncthreads();
  if (t < 96) {
    float S1 = sh1[0][t] + sh1[1][t], S2 = sh2[0][t] + sh2[1][t];
    float c = (float)max(end - beg, 1);
    float m = S1 / c;
    float mm = m * ms[t];
    float var = S2 / c - 2.f * mm * m + mm * mm;
    var = fmaxf(var, 0.f);
    meanms[g * 96 + t] = mm;
    inv[g * 96 + t] = rsqrtf(var + 1e-5f);
  }
}

// ---------------- normalize + residual: h_new = relu(gw*(z-mm)*inv+gb) + h_old ----------------

__global__ __launch_bounds__(256) void k_norm(const float* __restrict__ z, const float* __restrict__ h_old,
                                              const int* __restrict__ batch, const float* __restrict__ meanms,
                                              const float* __restrict__ inv, const float* __restrict__ gw,
                                              const float* __restrict__ gb, float* __restrict__ h_new) {
  int i = blockIdx.x * 256 + threadIdx.x;
  if (i >= Nn * 96) return;
  int n = i / 96, j = i % 96;
  int g = batch[n];
  float outv = z[i] - meanms[g * 96 + j];
  float zn = gw[j] * outv * inv[g * 96 + j] + gb[j];
  h_new[i] = fmaxf(zn, 0.f) + h_old[i];
}

// ---------------- pooling + LayerNorm + output MLP ----------------

__global__ __launch_bounds__(256) void k_pool_out(const float* __restrict__ h, const int* __restrict__ gptr,
                                                  const float* __restrict__ lng, const float* __restrict__ lnb,
                                                  const float* __restrict__ W1, const float* __restrict__ b1,
                                                  const float* __restrict__ W2, const float* __restrict__ b2,
                                                  float* __restrict__ out) {
  __shared__ float sh1[2][96], sh2[2][96];
  __shared__ float gbuf[192];
  __shared__ float rs[4], rq[4];
  __shared__ float s_mu, s_rstd;
  __shared__ float inter[96];
  int g = blockIdx.x, t = threadIdx.x;
  int beg = gptr[g], end = gptr[g + 1];
  if (t < 192) {
    int j = t % 96, half = t / 96;
    float s = 0.f, m = -INFINITY;
    for (int n = beg + half; n < end; n += 2) { float v = h[n * 96 + j]; s += v; m = fmaxf(m, v); }
    sh1[half][j] = s; sh2[half][j] = m;
  }
  __syncthreads();
  if (t < 96) {
    float c = (float)max(end - beg, 1);
    gbuf[t] = (sh1[0][t] + sh1[1][t]) / c;
    gbuf[96 + t] = fmaxf(sh2[0][t], sh2[1][t]);
  }
  __syncthreads();
  float sv = (t < 192) ? gbuf[t] : 0.f;
  float qv = sv * sv;
#pragma unroll
  for (int off = 32; off; off >>= 1) { sv += __shfl_down(sv, off); qv += __shfl_down(qv, off); }
  if ((t & 63) == 0) { rs[t >> 6] = sv; rq[t >> 6] = qv; }
  __syncthreads();
  if (t == 0) {
    float S = rs[0] + rs[1] + rs[2] + rs[3];
    float Q = rq[0] + rq[1] + rq[2] + rq[3];
    float mu = S / 192.f;
    float va = Q / 192.f - mu * mu;
    s_mu = mu; s_rstd = rsqrtf(fmaxf(va, 0.f) + 1e-5f);
  }
  __syncthreads();
  if (t < 192) gbuf[t] = (gbuf[t] - s_mu) * s_rstd * lng[t] + lnb[t];
  __syncthreads();
  if (t < 96) {
    float a = b1[t];
    for (int k = 0; k < 192; k++) a += gbuf[k] * W1[k * 96 + t];
    inter[t] = fmaxf(a, 0.f);
  }
  __syncthreads();
  {
    float a = b2[t];
    for (int j = 0; j < 96; j++) a += inter[j] * W2[j * 256 + t];
    out[g * 256 + t] = a;
  }
}

// ---------------- host ----------------

extern "C" void kernel_launch(void* const* d_in, const int* in_sizes, int n_in,
                              void* d_out, int out_size, void* d_ws, size_t ws_size,
                              hipStream_t stream) {
  (void)in_sizes; (void)n_in; (void)out_size;
  const float* x     = (const float*)d_in[0];
  const float* eattr = (const float*)d_in[1];
  const int*   eidx2 = (const int*)  d_in[2];
  const int*   batch = (const int*)  d_in[3];
  const float* nodeW = (const float*)d_in[4];
  const float* nodeb = (const float*)d_in[5];
  const float* edgeW = (const float*)d_in[6];
  const float* edgeb = (const float*)d_in[7];
  const float* mlpW1 = (const float*)d_in[8];
  const float* mlpb1 = (const float*)d_in[9];
  const float* mlpW2 = (const float*)d_in[10];
  const float* mlpb2 = (const float*)d_in[11];
  const float* epsA  = (const float*)d_in[12];
  const float* gnw   = (const float*)d_in[13];
  const float* gnb   = (const float*)d_in[14];
  const float* gnms  = (const float*)d_in[15];
  const float* lng   = (const float*)d_in[16];
  const float* lnb   = (const float*)d_in[17];
  const float* oW1   = (const float*)d_in[18];
  const float* ob1   = (const float*)d_in[19];
  const float* oW2   = (const float*)d_in[20];
  const float* ob2   = (const float*)d_in[21];
  float* out = (float*)d_out;

  const int* srcArr = eidx2;        // edge_index[0]
  const int* dstArr = eidx2 + Ee;   // edge_index[1]

  char* p = (char*)d_ws;
  auto carve = [&](size_t bytes) -> void* {
    void* r = (void*)p;
    p += ((bytes + 255) & ~(size_t)255);
    return r;
  };
  float* h_a   = (float*)carve((size_t)Nn * 96 * 4);
  float* h_b   = (float*)carve((size_t)Nn * 96 * 4);
  float* aggz  = (float*)carve((size_t)Nn * 96 * 4);  // agg, aliased as z
  int* rowptr  = (int*)carve((size_t)(Nn + 1) * 4);
  int* cursor  = (int*)carve((size_t)Nn * 4);
  int* deg     = (int*)carve((size_t)Nn * 4);
  int* localA  = (int*)carve((size_t)Nn * 4);
  int* bsum    = (int*)carve(512);
  int* elist   = (int*)carve((size_t)Ee * 4);
  int* gptr    = (int*)carve((size_t)(Gg + 1) * 4);
  float* meanms= (float*)carve((size_t)Gg * 96 * 4);
  float* invv  = (float*)carve((size_t)Gg * 96 * 4);
  int* srcPerm = (int*)carve((size_t)Ee * 4);
  __hip_bfloat16* ePerm = (__hip_bfloat16*)carve((size_t)Ee * 96 * 2);
  bool pre = ((size_t)(p - (char*)d_ws)) <= ws_size;   // fast path fits?

  hipMemsetAsync(deg, 0, (size_t)Nn * 4, stream);
  k_gptr<<<1, 512, 0, stream>>>(batch, gptr);
  k_deg<<<(Ee + 255) / 256, 256, 0, stream>>>(dstArr, deg);
  k_scanA<<<(Nn + 1023) / 1024, 256, 0, stream>>>(deg, localA, bsum);
  k_scanB<<<1, 64, 0, stream>>>(bsum);
  k_scanC<<<(Nn + 255) / 256, 256, 0, stream>>>(localA, bsum, rowptr, cursor);
  k_fill<<<(Ee + 255) / 256, 256, 0, stream>>>(dstArr, cursor, elist);

  if (pre)
    k_edge_mlp<<<(Ee + EB - 1) / EB, 192, 0, stream>>>(eattr, elist, srcArr, edgeW, edgeb, ePerm, srcPerm);

  k_node_mlp<<<(Nn + 15) / 16, 256, 0, stream>>>(x, nodeW, nodeb, h_a);

  float* hc = h_a;
  float* hn = h_b;
  for (int i = 0; i < 3; i++) {
    if (pre)
      k_agg_pre<<<Nn, 128, 0, stream>>>(hc, ePerm, srcPerm, rowptr, aggz);
    else
      k_agg<<<Nn, 128, 0, stream>>>(hc, eattr, srcArr, rowptr, elist, edgeW, edgeb, aggz);
    k_mlp<<<Nn / 32, 256, 0, stream>>>(hc, aggz, mlpW1 + i * 9216, mlpb1 + i * 96,
                                       mlpW2 + i * 9216, mlpb2 + i * 96, epsA, i, aggz);
    k_stats<<<Gg, 192, 0, stream>>>(aggz, gptr, gnms + i * 96, meanms, invv);
    k_norm<<<(Nn * 96 + 255) / 256, 256, 0, stream>>>(aggz, hc, batch, meanms, invv,
                                                      gnw + i * 96, gnb + i * 96, hn);
    float* tmp = hc; hc = hn; hn = tmp;
  }

  k_pool_out<<<Gg, 256, 0, stream>>>(hc, gptr, lng, lnb, oW1, ob1, oW2, ob2, out);
}

// Round 5
// 1073.370 us; speedup vs baseline: 1.2348x; 1.1157x over previous
//
#include <hip/hip_runtime.h>
#include <hip/hip_bf16.h>
#include <cfloat>

#define Nn 100000
#define Ee 800000
#define Gg 256
// H=96, NI=32, EI=10, OUT=256, L=3

// ---------------- CSR build ----------------

__global__ __launch_bounds__(512) void k_gptr(const int* __restrict__ batch, int* __restrict__ gptr) {
  int g = threadIdx.x;
  if (g > Gg) return;
  if (g == Gg) { gptr[Gg] = Nn; return; }
  int lo = 0, hi = Nn;
  while (lo < hi) { int mid = (lo + hi) >> 1; if (batch[mid] < g) lo = mid + 1; else hi = mid; }
  gptr[g] = lo;
}

__global__ __launch_bounds__(256) void k_deg(const int* __restrict__ dst, int* __restrict__ deg) {
  int e = blockIdx.x * 256 + threadIdx.x;
  if (e < Ee) atomicAdd(&deg[dst[e]], 1);
}

// block scans 1024 elements (4/thread, 256 threads)
__global__ __launch_bounds__(256) void k_scanA(const int* __restrict__ deg, int* __restrict__ localA,
                                               int* __restrict__ bsum) {
  __shared__ int ts[256];
  int t = threadIdx.x, b = blockIdx.x;
  int base = b * 1024 + t * 4;
  int v[4]; int s = 0;
#pragma unroll
  for (int k = 0; k < 4; k++) { int idx = base + k; v[k] = (idx < Nn) ? deg[idx] : 0; s += v[k]; }
  ts[t] = s; __syncthreads();
  for (int off = 1; off < 256; off <<= 1) {
    int y = (t >= off) ? ts[t - off] : 0;
    __syncthreads();
    ts[t] += y;
    __syncthreads();
  }
  int ex = ts[t] - s;  // exclusive prefix for this thread's chunk
#pragma unroll
  for (int k = 0; k < 4; k++) { int idx = base + k; if (idx < Nn) localA[idx] = ex; ex += v[k]; }
  if (t == 255) bsum[b] = ts[255];
}

__global__ void k_scanB(int* __restrict__ bsum) {
  if (threadIdx.x == 0) {
    const int NB = (Nn + 1023) / 1024;
    int acc = 0;
    for (int b = 0; b < NB; b++) { int v = bsum[b]; bsum[b] = acc; acc += v; }
  }
}

__global__ __launch_bounds__(256) void k_scanC(const int* __restrict__ localA, const int* __restrict__ bsum,
                                               int* __restrict__ rowptr, int* __restrict__ cursor) {
  int i = blockIdx.x * 256 + threadIdx.x;
  if (i < Nn) { int v = localA[i] + bsum[i >> 10]; rowptr[i] = v; cursor[i] = v; }
  if (i == 0) rowptr[Nn] = Ee;
}

__global__ __launch_bounds__(256) void k_fill(const int* __restrict__ dst, int* __restrict__ cursor,
                                              int* __restrict__ elist) {
  int e = blockIdx.x * 256 + threadIdx.x;
  if (e < Ee) { int p = atomicAdd(&cursor[dst[e]], 1); elist[p] = e; }
}

// ---------------- edge MLP precompute (layer-invariant): ePerm[q] = relu(eattr[elist[q]]@eW+eb) ----------------
// Also builds srcPerm[q] = srcArr[elist[q]] so k_agg streams both contiguously.
// NOTE: srcPerm overlays the (dead) CSR temporaries; k_edge_mlp runs after k_fill.

#define EB 128

__global__ __launch_bounds__(192) void k_edge_mlp(const float* __restrict__ eattr, const int* __restrict__ elist,
                                                  const int* __restrict__ srcArr, const float* __restrict__ eW,
                                                  const float* __restrict__ eb, __hip_bfloat16* __restrict__ ePerm,
                                                  int* __restrict__ srcPerm) {
  __shared__ float ea[EB][10];
  __shared__ float Ws[10 * 96];
  __shared__ float bs[96];
  int t = threadIdx.x;
  int q0 = blockIdx.x * EB;
  int m = min(EB, Ee - q0);
  for (int i = t; i < 960; i += 192) Ws[i] = eW[i];
  if (t < 96) bs[t] = eb[t];
  for (int i = t; i < m; i += 192) srcPerm[q0 + i] = srcArr[elist[q0 + i]];
  for (int i = t; i < 10 * m; i += 192) {
    int ii = i / 10, k = i - ii * 10;
    int e = elist[q0 + ii];             // redundant load, L1-hit
    ea[ii][k] = eattr[e * 10 + k];
  }
  __syncthreads();
  int j = t % 96, sub = t / 96;         // sub in {0,1}
  for (int i = sub; i < m; i += 2) {
    float acc = bs[j];
#pragma unroll
    for (int k = 0; k < 10; k++) acc += ea[i][k] * Ws[k * 96 + j];
    ePerm[(size_t)(q0 + i) * 96 + j] = __float2bfloat16(fmaxf(acc, 0.f));
  }
}

// ---------------- node MLP: h = relu(x @ W + b), x[N,32], W[32,96] ----------------

__global__ __launch_bounds__(256) void k_node_mlp(const float* __restrict__ x, const float* __restrict__ W,
                                                  const float* __restrict__ b, float* __restrict__ h) {
  __shared__ float xs[16][33];
  __shared__ float Ws[32 * 96];
  __shared__ float bs[96];
  int t = threadIdx.x;
  int n0 = blockIdx.x * 16;
  for (int i = t; i < 32 * 96; i += 256) Ws[i] = W[i];
  if (t < 96) bs[t] = b[t];
  for (int i = t; i < 512; i += 256) {
    int nl = i >> 5, k = i & 31; int n = n0 + nl;
    xs[nl][k] = (n < Nn) ? x[n * 32 + k] : 0.f;
  }
  __syncthreads();
#pragma unroll
  for (int p = 0; p < 6; p++) {
    int oi = t + p * 256; int nl = oi / 96, j = oi % 96; int n = n0 + nl;
    if (n < Nn) {
      float acc = bs[j];
#pragma unroll
      for (int k = 0; k < 32; k++) acc += xs[nl][k] * Ws[k * 96 + j];
      h[n * 96 + j] = fmaxf(acc, 0.f);
    }
  }
}

// ---------------- aggregation (fast path): agg[nd] = sum relu(h[srcPerm[q]] + ePerm[q]) ----------------
// Edge messages pre-reluted in ePerm (bf16, contiguous in q). Inner loop: 1 gather + 1 stream.

#define ACHUNK 32

__global__ __launch_bounds__(128) void k_agg_pre(const float* __restrict__ h,
                                                 const __hip_bfloat16* __restrict__ ePerm,
                                                 const int* __restrict__ srcPerm,
                                                 const int* __restrict__ rowptr,
                                                 float* __restrict__ agg) {
  __shared__ int sL[ACHUNK];
  int t = threadIdx.x;
  int nd = blockIdx.x;
  int beg = rowptr[nd], end = rowptr[nd + 1];
  float acc = 0.f;
  for (int cs = beg; cs < end; cs += ACHUNK) {
    int m = min(ACHUNK, end - cs);
    __syncthreads();   // previous iteration's reads of sL done
    if (t < m) sL[t] = srcPerm[cs + t];
    __syncthreads();
    if (t < 96) {
#pragma unroll 4
      for (int i = 0; i < m; i++) {
        int src = sL[i];
        float hv = h[src * 96 + t];
        float ef = __bfloat162float(ePerm[(size_t)(cs + i) * 96 + t]);
        acc += fmaxf(hv + ef, 0.f);
      }
    }
  }
  if (t < 96) agg[nd * 96 + t] = acc;
}

// ---------------- aggregation (fallback, round-2 proven): recompute edge MLP on the fly ----------------

__global__ __launch_bounds__(128) void k_agg(const float* __restrict__ h, const float* __restrict__ eattr,
                                             const int* __restrict__ srcArr, const int* __restrict__ rowptr,
                                             const int* __restrict__ elist, const float* __restrict__ eW,
                                             const float* __restrict__ eb, float* __restrict__ agg) {
  __shared__ float Ws[10 * 96];
  __shared__ float bs_s[96];
  __shared__ int sL[ACHUNK];
  __shared__ float eaL[ACHUNK][10];
  int t = threadIdx.x;
  int nd = blockIdx.x;
  for (int i = t; i < 960; i += 128) Ws[i] = eW[i];
  if (t < 96) bs_s[t] = eb[t];
  int beg = rowptr[nd], end = rowptr[nd + 1];
  float acc = 0.f;
  for (int cs = beg; cs < end; cs += ACHUNK) {
    int m = min(ACHUNK, end - cs);
    __syncthreads();
    if (t < m) sL[t] = srcArr[elist[cs + t]];
    for (int i = t; i < 10 * m; i += 128) {
      int ii = i / 10, k = i - ii * 10;
      int e = elist[cs + ii];
      eaL[ii][k] = eattr[e * 10 + k];
    }
    __syncthreads();
    if (t < 96) {
#pragma unroll 4
      for (int i = 0; i < m; i++) {
        int src = sL[i];
        float ej = bs_s[t];
#pragma unroll
        for (int k = 0; k < 10; k++) ej += eaL[i][k] * Ws[k * 96 + t];
        ej = fmaxf(ej, 0.f);
        acc += fmaxf(h[src * 96 + t] + ej, 0.f);
      }
    }
  }
  if (t < 96) agg[nd * 96 + t] = acc;
}

// ---------------- per-layer MLP: z = relu(z0@W1+b1)@W2+b2, z0 = (1+eps)*h + agg ----------------
// NOTE: agg and z alias (block reads only its own rows before writing them).

__global__ __launch_bounds__(256) void k_mlp(const float* __restrict__ h, const float* agg,
                                             const float* __restrict__ W1, const float* __restrict__ b1,
                                             const float* __restrict__ W2, const float* __restrict__ b2,
                                             const float* __restrict__ epsA, int layer, float* z) {
  __shared__ float in_s[32][97];
  __shared__ float mid[32][97];
  __shared__ float Ws[96 * 96];
  int t = threadIdx.x;
  int n0 = blockIdx.x * 32;
  float epsv = 1.0f + epsA[layer];
  for (int i = t; i < 3072; i += 256) {
    int nl = i / 96, k = i % 96; int n = n0 + nl;
    in_s[nl][k] = (n < Nn) ? (epsv * h[n * 96 + k] + agg[n * 96 + k]) : 0.f;
  }
  for (int i = t; i < 9216; i += 256) Ws[i] = W1[i];
  __syncthreads();
  int nl = t >> 3, jb = t & 7;   // node, feature-block
  float acc[12];
#pragma unroll
  for (int jj = 0; jj < 12; jj++) acc[jj] = b1[jb * 12 + jj];
  for (int k = 0; k < 96; k++) {
    float a = in_s[nl][k];
#pragma unroll
    for (int jj = 0; jj < 12; jj++) acc[jj] += a * Ws[k * 96 + jb * 12 + jj];
  }
#pragma unroll
  for (int jj = 0; jj < 12; jj++) mid[nl][jb * 12 + jj] = fmaxf(acc[jj], 0.f);
  __syncthreads();               // all reads of Ws (W1) done
  for (int i = t; i < 9216; i += 256) Ws[i] = W2[i];
  __syncthreads();
#pragma unroll
  for (int jj = 0; jj < 12; jj++) acc[jj] = b2[jb * 12 + jj];
  for (int k = 0; k < 96; k++) {
    float a = mid[nl][k];
#pragma unroll
    for (int jj = 0; jj < 12; jj++) acc[jj] += a * Ws[k * 96 + jb * 12 + jj];
  }
  int n = n0 + nl;
  if (n < Nn) {
#pragma unroll
    for (int jj = 0; jj < 12; jj++) z[n * 96 + jb * 12 + jj] = acc[jj];
  }
}

// ---------------- GraphNorm stats: meanms = (S1/c)*ms ; inv = rsqrt(var+1e-5) ----------------

__global__ __launch_bounds__(192) void k_stats(const float* __restrict__ z, const int* __restrict__ gptr,
                                               const float* __restrict__ ms, float* __restrict__ meanms,
                                               float* __restrict__ inv) {
  __shared__ float sh1[2][96], sh2[2][96];
  int g = blockIdx.x, t = threadIdx.x;
  int j = t % 96, half = t / 96;
  int beg = gptr[g], end = gptr[g + 1];
  float s1 = 0.f, s2 = 0.f;
  for (int n = beg + half; n < end; n += 2) { float v = z[n * 96 + j]; s1 += v; s2 += v * v; }
  sh1[half][j] = s1; sh2[half][j] = s2;
  __syncthreads();
  if (t < 96) {
    float S1 = sh1[0][t] + sh1[1][t], S2 = sh2[0][t] + sh2[1][t];
    float c = (float)max(end - beg, 1);
    float m = S1 / c;
    float mm = m * ms[t];
    float var = S2 / c - 2.f * mm * m + mm * mm;
    var = fmaxf(var, 0.f);
    meanms[g * 96 + t] = mm;
    inv[g * 96 + t] = rsqrtf(var + 1e-5f);
  }
}

// ---------------- normalize + residual (IN-PLACE over h): h[i] = relu(gw*(z-mm)*inv+gb) + h[i] ----------------

__global__ __launch_bounds__(256) void k_norm(const float* __restrict__ z, float* __restrict__ h_io,
                                              const int* __restrict__ batch, const float* __restrict__ meanms,
                                              const float* __restrict__ inv, const float* __restrict__ gw,
                                              const float* __restrict__ gb) {
  int i = blockIdx.x * 256 + threadIdx.x;
  if (i >= Nn * 96) return;
  int n = i / 96, j = i % 96;
  int g = batch[n];
  float outv = z[i] - meanms[g * 96 + j];
  float zn = gw[j] * outv * inv[g * 96 + j] + gb[j];
  h_io[i] = fmaxf(zn, 0.f) + h_io[i];   // elementwise read-then-write, alias-safe
}

// ---------------- pooling + LayerNorm + output MLP ----------------

__global__ __launch_bounds__(256) void k_pool_out(const float* __restrict__ h, const int* __restrict__ gptr,
                                                  const float* __restrict__ lng, const float* __restrict__ lnb,
                                                  const float* __restrict__ W1, const float* __restrict__ b1,
                                                  const float* __restrict__ W2, const float* __restrict__ b2,
                                                  float* __restrict__ out) {
  __shared__ float sh1[2][96], sh2[2][96];
  __shared__ float gbuf[192];
  __shared__ float rs[4], rq[4];
  __shared__ float s_mu, s_rstd;
  __shared__ float inter[96];
  int g = blockIdx.x, t = threadIdx.x;
  int beg = gptr[g], end = gptr[g + 1];
  if (t < 192) {
    int j = t % 96, half = t / 96;
    float s = 0.f, m = -INFINITY;
    for (int n = beg + half; n < end; n += 2) { float v = h[n * 96 + j]; s += v; m = fmaxf(m, v); }
    sh1[half][j] = s; sh2[half][j] = m;
  }
  __syncthreads();
  if (t < 96) {
    float c = (float)max(end - beg, 1);
    gbuf[t] = (sh1[0][t] + sh1[1][t]) / c;
    gbuf[96 + t] = fmaxf(sh2[0][t], sh2[1][t]);
  }
  __syncthreads();
  float sv = (t < 192) ? gbuf[t] : 0.f;
  float qv = sv * sv;
#pragma unroll
  for (int off = 32; off; off >>= 1) { sv += __shfl_down(sv, off); qv += __shfl_down(qv, off); }
  if ((t & 63) == 0) { rs[t >> 6] = sv; rq[t >> 6] = qv; }
  __syncthreads();
  if (t == 0) {
    float S = rs[0] + rs[1] + rs[2] + rs[3];
    float Q = rq[0] + rq[1] + rq[2] + rq[3];
    float mu = S / 192.f;
    float va = Q / 192.f - mu * mu;
    s_mu = mu; s_rstd = rsqrtf(fmaxf(va, 0.f) + 1e-5f);
  }
  __syncthreads();
  if (t < 192) gbuf[t] = (gbuf[t] - s_mu) * s_rstd * lng[t] + lnb[t];
  __syncthreads();
  if (t < 96) {
    float a = b1[t];
    for (int k = 0; k < 192; k++) a += gbuf[k] * W1[k * 96 + t];
    inter[t] = fmaxf(a, 0.f);
  }
  __syncthreads();
  {
    float a = b2[t];
    for (int j = 0; j < 96; j++) a += inter[j] * W2[j * 256 + t];
    out[g * 256 + t] = a;
  }
}

// ---------------- host ----------------

extern "C" void kernel_launch(void* const* d_in, const int* in_sizes, int n_in,
                              void* d_out, int out_size, void* d_ws, size_t ws_size,
                              hipStream_t stream) {
  (void)in_sizes; (void)n_in; (void)out_size;
  const float* x     = (const float*)d_in[0];
  const float* eattr = (const float*)d_in[1];
  const int*   eidx2 = (const int*)  d_in[2];
  const int*   batch = (const int*)  d_in[3];
  const float* nodeW = (const float*)d_in[4];
  const float* nodeb = (const float*)d_in[5];
  const float* edgeW = (const float*)d_in[6];
  const float* edgeb = (const float*)d_in[7];
  const float* mlpW1 = (const float*)d_in[8];
  const float* mlpb1 = (const float*)d_in[9];
  const float* mlpW2 = (const float*)d_in[10];
  const float* mlpb2 = (const float*)d_in[11];
  const float* epsA  = (const float*)d_in[12];
  const float* gnw   = (const float*)d_in[13];
  const float* gnb   = (const float*)d_in[14];
  const float* gnms  = (const float*)d_in[15];
  const float* lng   = (const float*)d_in[16];
  const float* lnb   = (const float*)d_in[17];
  const float* oW1   = (const float*)d_in[18];
  const float* ob1   = (const float*)d_in[19];
  const float* oW2   = (const float*)d_in[20];
  const float* ob2   = (const float*)d_in[21];
  float* out = (float*)d_out;

  const int* srcArr = eidx2;        // edge_index[0]
  const int* dstArr = eidx2 + Ee;   // edge_index[1]

  char* p = (char*)d_ws;
  auto carve = [&](size_t bytes) -> void* {
    void* r = (void*)p;
    p += ((bytes + 255) & ~(size_t)255);
    return r;
  };
  // Essentials (always fit):
  float* h_a   = (float*)carve((size_t)Nn * 96 * 4);   // h  (in-place residual)
  float* aggz  = (float*)carve((size_t)Nn * 96 * 4);   // agg, aliased as z
  int* rowptr  = (int*)carve((size_t)(Nn + 1) * 4);
  int* elist   = (int*)carve((size_t)Ee * 4);
  int* gptr    = (int*)carve((size_t)(Gg + 1) * 4);
  float* meanms= (float*)carve((size_t)Gg * 96 * 4);
  float* invv  = (float*)carve((size_t)Gg * 96 * 4);
  // srcPerm (Ee ints) doubles as CSR temp space (deg/localA/cursor/bsum, 3*Nn+NB ints < Ee).
  int* srcPerm = (int*)carve((size_t)Ee * 4);
  int* deg     = srcPerm;
  int* localA  = srcPerm + Nn;
  int* cursor  = srcPerm + 2 * Nn;
  int* bsum    = srcPerm + 3 * Nn;
  // Optional (fast path): bf16 precomputed edge messages, in elist order.
  __hip_bfloat16* ePerm = (__hip_bfloat16*)carve((size_t)Ee * 96 * 2);
  bool pre = ((size_t)(p - (char*)d_ws)) <= ws_size;   // fast path fits?

  hipMemsetAsync(deg, 0, (size_t)Nn * 4, stream);
  k_gptr<<<1, 512, 0, stream>>>(batch, gptr);
  k_deg<<<(Ee + 255) / 256, 256, 0, stream>>>(dstArr, deg);
  k_scanA<<<(Nn + 1023) / 1024, 256, 0, stream>>>(deg, localA, bsum);
  k_scanB<<<1, 64, 0, stream>>>(bsum);
  k_scanC<<<(Nn + 255) / 256, 256, 0, stream>>>(localA, bsum, rowptr, cursor);
  k_fill<<<(Ee + 255) / 256, 256, 0, stream>>>(dstArr, cursor, elist);

  if (pre)   // overwrites the CSR temps (dead) with srcPerm
    k_edge_mlp<<<(Ee + EB - 1) / EB, 192, 0, stream>>>(eattr, elist, srcArr, edgeW, edgeb, ePerm, srcPerm);

  k_node_mlp<<<(Nn + 15) / 16, 256, 0, stream>>>(x, nodeW, nodeb, h_a);

  for (int i = 0; i < 3; i++) {
    if (pre)
      k_agg_pre<<<Nn, 128, 0, stream>>>(h_a, ePerm, srcPerm, rowptr, aggz);
    else
      k_agg<<<Nn, 128, 0, stream>>>(h_a, eattr, srcArr, rowptr, elist, edgeW, edgeb, aggz);
    k_mlp<<<Nn / 32, 256, 0, stream>>>(h_a, aggz, mlpW1 + i * 9216, mlpb1 + i * 96,
                                       mlpW2 + i * 9216, mlpb2 + i * 96, epsA, i, aggz);
    k_stats<<<Gg, 192, 0, stream>>>(aggz, gptr, gnms + i * 96, meanms, invv);
    k_norm<<<(Nn * 96 + 255) / 256, 256, 0, stream>>>(aggz, h_a, batch, meanms, invv,
                                                      gnw + i * 96, gnb + i * 96);
  }

  k_pool_out<<<Gg, 256, 0, stream>>>(h_a, gptr, lng, lnb, oW1, ob1, oW2, ob2, out);
}